// Round 1
// baseline (443.534 us; speedup 1.0000x reference)
//
#include <hip/hip_runtime.h>

#define NN 80
#define NPAIR (NN * NN)          // 6400
#define MAXIT 60
#define TOLV 1e-3f

// Block-wide sum over 256 threads (4 waves of 64). Result returned to ALL threads.
__device__ __forceinline__ float block_reduce_sum(float part, float* red) {
    const int lane = threadIdx.x & 63;
    const int wid  = threadIdx.x >> 6;
#pragma unroll
    for (int off = 32; off > 0; off >>= 1)
        part += __shfl_down(part, off, 64);
    if (lane == 0) red[wid] = part;
    __syncthreads();
    float r = red[0] + red[1] + red[2] + red[3];
    __syncthreads();   // protect red[] for the next call
    return r;
}

template <bool ATOMIC>
__global__ __launch_bounds__(256) void pair_kernel(
    const float* __restrict__ r_zeros,
    const float* __restrict__ r_const,
    const float* __restrict__ t_paths,
    const float* __restrict__ weights_t,
    const float* __restrict__ weights_r,
    float* __restrict__ outbuf)   // ATOMIC: [NN] output; else [NPAIR][NN] deltas
{
    __shared__ float A[NN][NN + 1];   // +1 pad: matvec row reads hit distinct banks
    __shared__ float v[NN];
    __shared__ float Av[NN];
    __shared__ float red[4];

    const int p   = blockIdx.x;
    const int tid = threadIdx.x;
    const long base = (long)p * (NN * NN);

    // ---- Stage A = weights_r * r_zeros + r_const into LDS (coalesced float4) ----
    const float4* wr4 = (const float4*)(weights_r + base);
    const float4* rz4 = (const float4*)(r_zeros + base);
    const float4* rc4 = (const float4*)(r_const + base);
    for (int c = tid; c < (NN * NN) / 4; c += 256) {
        float4 a = wr4[c];
        float4 b = rz4[c];
        float4 d = rc4[c];
        const int f = c * 4;            // NN % 4 == 0 -> float4 never crosses a row
        const int row = f / NN, col = f % NN;
        A[row][col + 0] = fmaf(a.x, b.x, d.x);
        A[row][col + 1] = fmaf(a.y, b.y, d.y);
        A[row][col + 2] = fmaf(a.z, b.z, d.z);
        A[row][col + 3] = fmaf(a.w, b.w, d.w);
    }
    if (tid < NN) v[tid] = 0.11180339887498949f;   // 1/sqrt(80)
    __syncthreads();

    // ---- Av = A v ; ev0 = v.Av ----
    if (tid < NN) {
        float s = 0.f;
#pragma unroll
        for (int j = 0; j < NN; ++j) s = fmaf(A[tid][j], v[j], s);
        Av[tid] = s;
    }
    __syncthreads();
    float part = (tid < NN) ? v[tid] * Av[tid] : 0.f;
    float ev = block_reduce_sum(part, red);

    // ---- Power iteration with reference's convergence/freeze semantics ----
    for (int it = 0; it < MAXIT; ++it) {
        part = (tid < NN) ? Av[tid] * Av[tid] : 0.f;
        const float inv = 1.f / sqrtf(block_reduce_sum(part, red));
        if (tid < NN) v[tid] = Av[tid] * inv;      // v_new
        __syncthreads();
        if (tid < NN) {
            float s = 0.f;
#pragma unroll
            for (int j = 0; j < NN; ++j) s = fmaf(A[tid][j], v[j], s);
            Av[tid] = s;                            // A v_new (reused next iter)
        }
        __syncthreads();
        part = (tid < NN) ? v[tid] * Av[tid] : 0.f;
        const float ev_new = block_reduce_sum(part, red);   // uniform across block
        if (fabsf(ev - ev_new) < TOLV) break;       // ref returns v_new at this step
        ev = ev_new;
    }

    // ---- deltas = v * (T_val / v[src]) ----
    const int s_idx = p / NN;
    const float T = weights_t[p] * t_paths[p];
    const float scale = T / v[s_idx];
    if (tid < NN) {
        const float dv = v[tid] * scale;
        if (ATOMIC) atomicAdd(&outbuf[tid], dv);
        else        outbuf[(long)p * NN + tid] = dv;
    }
}

__global__ __launch_bounds__(256) void reduce_kernel(
    const float* __restrict__ deltas, float* __restrict__ out)
{
    __shared__ float red[4];
    const int j = blockIdx.x;          // one output column per block
    float part = 0.f;
    for (int p = threadIdx.x; p < NPAIR; p += 256)
        part += deltas[(long)p * NN + j];
    const int lane = threadIdx.x & 63;
    const int wid  = threadIdx.x >> 6;
#pragma unroll
    for (int off = 32; off > 0; off >>= 1)
        part += __shfl_down(part, off, 64);
    if (lane == 0) red[wid] = part;
    __syncthreads();
    if (threadIdx.x == 0) out[j] = red[0] + red[1] + red[2] + red[3];
}

extern "C" void kernel_launch(void* const* d_in, const int* in_sizes, int n_in,
                              void* d_out, int out_size, void* d_ws, size_t ws_size,
                              hipStream_t stream) {
    // setup_inputs order: x, r_zeros, r_const, t_paths, weights_t, weights_r
    const float* r_zeros   = (const float*)d_in[1];
    const float* r_const   = (const float*)d_in[2];
    const float* t_paths   = (const float*)d_in[3];
    const float* weights_t = (const float*)d_in[4];
    const float* weights_r = (const float*)d_in[5];
    float* out = (float*)d_out;

    const size_t need = (size_t)NPAIR * NN * sizeof(float);
    if (ws_size >= need) {
        float* deltas = (float*)d_ws;
        pair_kernel<false><<<NPAIR, 256, 0, stream>>>(
            r_zeros, r_const, t_paths, weights_t, weights_r, deltas);
        reduce_kernel<<<NN, 256, 0, stream>>>(deltas, out);
    } else {
        hipMemsetAsync(d_out, 0, NN * sizeof(float), stream);
        pair_kernel<true><<<NPAIR, 256, 0, stream>>>(
            r_zeros, r_const, t_paths, weights_t, weights_r, out);
    }
}